// Round 1
// baseline (650.522 us; speedup 1.0000x reference)
//
#include <hip/hip_runtime.h>

typedef __bf16 bf16;
typedef __bf16 bf16x8 __attribute__((ext_vector_type(8)));
typedef float  f32x4  __attribute__((ext_vector_type(4)));

#define MFMA16(a, b, c) __builtin_amdgcn_mfma_f32_16x16x32_bf16((a), (b), (c), 0, 0, 0)

// async global->LDS, 16B per lane; LDS dest = wave-uniform base + lane*16
#define GLOAD_LDS16(gptr, lptr)                                              \
    __builtin_amdgcn_global_load_lds(                                        \
        (const __attribute__((address_space(1))) unsigned int*)(gptr),       \
        (__attribute__((address_space(3))) unsigned int*)(lptr), 16, 0, 0)

constexpr int kDM = 1024;
constexpr int kNTOK = 32768;   // V token count (vt row stride)

static __device__ inline f32x4 zero4() { f32x4 z = {0.f, 0.f, 0.f, 0.f}; return z; }

// ---------------------------------------------------------------------------
// All three W fp32 [k][n] -> Wt bf16 [n][k] transposes in one launch.
// ---------------------------------------------------------------------------
__global__ __launch_bounds__(256) void transpose_all(
    const float* __restrict__ Wq, const float* __restrict__ Wk,
    const float* __restrict__ Wv, bf16* __restrict__ Wqt,
    bf16* __restrict__ Wkt, bf16* __restrict__ Wvt)
{
    __shared__ bf16 T[64][68];
    const float* W = (blockIdx.z == 0) ? Wq : (blockIdx.z == 1) ? Wk : Wv;
    bf16* Wt       = (blockIdx.z == 0) ? Wqt : (blockIdx.z == 1) ? Wkt : Wvt;
    const int tid = threadIdx.x;
    const int n0 = blockIdx.x * 64, k0 = blockIdx.y * 64;
    #pragma unroll
    for (int i = 0; i < 4; i++) {
        const int kk = (tid >> 4) + i * 16, nn4 = (tid & 15) * 4;
        float4 v = *(const float4*)&W[(size_t)(k0 + kk) * kDM + n0 + nn4];
        T[nn4 + 0][kk] = (bf16)v.x; T[nn4 + 1][kk] = (bf16)v.y;
        T[nn4 + 2][kk] = (bf16)v.z; T[nn4 + 3][kk] = (bf16)v.w;
    }
    __syncthreads();
    #pragma unroll
    for (int i = 0; i < 4; i++) {
        const int nn = (tid >> 4) + i * 16, kc = (tid & 15) * 4;
        *(ushort4*)&Wt[(size_t)(n0 + nn) * kDM + k0 + kc] = *(const ushort4*)&T[nn][kc];
    }
}

// ---------------------------------------------------------------------------
// GEMM + fused epilogue, 256x256 tile, BK=64, 512 threads = 8 waves (2Mx4N).
// Per wave: 128x64 output = acc[8][4] f32x4.  LDS 128KB:
//   A: 2 x [256][64] bf16 (reg-staged from fp32 X with inline cvt; LDS write
//      16B-slot XOR-swizzled by row&7 -> <=2-way conflicts on frag reads)
//   B: 2 x [256][64] bf16 (global_load_lds w=16, pre-swizzled global source)
// Pipeline (depth 1, counted): issue A-loads(t+1)+B-gld(t+1) at top, compute
// tile t (64 MFMA/wave), ds_write A(t+1), then lgkmcnt(0)/vmcnt(0)/s_barrier.
// Raw s_barrier (no __syncthreads drain) keeps the prefetch in flight across
// the whole compute phase.
// MODE 1: slow RoPE (q).  MODE 2: fast RoPE (k).  MODE 3: V^T store.
// Epilogue reuses LDS as Y, one 128-col half (one head for RoPE) at a time.
// ---------------------------------------------------------------------------
template <int MODE>
__global__ __launch_bounds__(512, 2) void gemm_fused(
    const float* __restrict__ X, const bf16* __restrict__ Wt,
    const float* __restrict__ bias, bf16* __restrict__ out, int mtiles_per_xcd)
{
    __shared__ char smem[131072];

    const int b    = blockIdx.x;
    const int xcd  = b & 7;
    const int s    = b >> 3;
    const int m0   = (xcd * mtiles_per_xcd + (s >> 2)) * 256;
    const int n0   = (s & 3) * 256;
    const int tid  = threadIdx.x;
    const int wave = tid >> 6;
    const int lane = tid & 63;
    const int quad = lane >> 4, l16 = lane & 15;
    const int wr   = wave >> 2;        // 0..1  (M half)
    const int wc   = wave & 3;         // 0..3  (N quarter)

    // A reg-staging coords: thread covers 4 (row,slot) 16B slots
    const int arow  = tid >> 3;                    // 0..63 base row
    const int as8   = tid & 7;                     // source 16B slot
    const int awoff = (as8 ^ (arow & 7)) * 8;      // swizzled LDS slot (elems)
    const float* xbase = X + (size_t)(m0 + arow) * kDM + as8 * 8;
    // B staging: 4 chunks per wave, 1KB each (8 rows x 8 slots)
    const int bc0 = wave * 4;

    f32x4 acc[8][4];
    #pragma unroll
    for (int i = 0; i < 8; i++)
        #pragma unroll
        for (int j = 0; j < 4; j++) acc[i][j] = zero4();

    // ---- prologue: stage tile 0 into buffer 0 ----
    {
        #pragma unroll
        for (int i = 0; i < 4; i++) {
            const int row = (bc0 + i) * 8 + (lane >> 3);
            GLOAD_LDS16(&Wt[(size_t)(n0 + row) * kDM + (((lane & 7) ^ (row & 7)) * 8)],
                        (bf16*)(smem + 65536) + (bc0 + i) * 512);
        }
        #pragma unroll
        for (int p = 0; p < 4; p++) {
            const float* src = xbase + (size_t)p * 64 * kDM;
            float4 u0 = *(const float4*)src;
            float4 u1 = *(const float4*)(src + 4);
            bf16x8 w;
            #pragma unroll
            for (int e = 0; e < 4; e++) { w[e] = (bf16)u0[e]; w[4 + e] = (bf16)u1[e]; }
            *(bf16x8*)&((bf16*)smem)[(p * 64 + arow) * 64 + awoff] = w;
        }
        asm volatile("s_waitcnt lgkmcnt(0)" ::: "memory");
        asm volatile("s_waitcnt vmcnt(0)" ::: "memory");
        __builtin_amdgcn_s_barrier();
    }

    // ---- main loop over 16 K-tiles ----
    for (int t = 0; t < 16; ++t) {
        const int bt = t & 1;
        bf16* Ac = (bf16*)(smem + bt * 32768);
        bf16* An = (bf16*)(smem + (bt ^ 1) * 32768);
        bf16* Bc = (bf16*)(smem + 65536 + bt * 32768);
        bf16* Bn = (bf16*)(smem + 65536 + (bt ^ 1) * 32768);

        float4 av[8];
        if (t < 15) {
            const int k1 = (t + 1) * 64;
            #pragma unroll
            for (int p = 0; p < 4; p++) {            // A(t+1) -> regs
                const float* src = xbase + (size_t)p * 64 * kDM + k1;
                av[p * 2]     = *(const float4*)src;
                av[p * 2 + 1] = *(const float4*)(src + 4);
            }
            #pragma unroll
            for (int i = 0; i < 4; i++) {            // B(t+1) -> LDS (async)
                const int row = (bc0 + i) * 8 + (lane >> 3);
                GLOAD_LDS16(&Wt[(size_t)(n0 + row) * kDM + k1 + (((lane & 7) ^ (row & 7)) * 8)],
                            Bn + (bc0 + i) * 512);
            }
        }
        __builtin_amdgcn_sched_barrier(0);           // keep prefetch issue above compute

        #pragma unroll
        for (int ks = 0; ks < 2; ++ks) {
            bf16x8 a[8], bq[4];
            const int G = ks * 4 + quad;
            #pragma unroll
            for (int i = 0; i < 8; i++)
                a[i] = *(const bf16x8*)&Ac[(wr * 128 + i * 16 + l16) * 64 + ((G ^ (l16 & 7)) * 8)];
            #pragma unroll
            for (int j = 0; j < 4; j++)
                bq[j] = *(const bf16x8*)&Bc[(wc * 64 + j * 16 + l16) * 64 + ((G ^ (l16 & 7)) * 8)];
            #pragma unroll
            for (int i = 0; i < 8; i++)
                #pragma unroll
                for (int j = 0; j < 4; j++)
                    acc[i][j] = MFMA16(a[i], bq[j], acc[i][j]);
        }

        if (t < 15) {                                // deposit A(t+1) to LDS
            #pragma unroll
            for (int p = 0; p < 4; p++) {
                bf16x8 w;
                #pragma unroll
                for (int e = 0; e < 4; e++) {
                    w[e]     = (bf16)av[p * 2][e];
                    w[4 + e] = (bf16)av[p * 2 + 1][e];
                }
                *(bf16x8*)&An[(p * 64 + arow) * 64 + awoff] = w;
            }
        }
        asm volatile("s_waitcnt lgkmcnt(0)" ::: "memory");
        asm volatile("s_waitcnt vmcnt(0)" ::: "memory");
        __builtin_amdgcn_s_barrier();
    }

    // ---- epilogue ----
    if (MODE == 3) {
        // transposed store: Y[nl][m] per 128-col half, then coalesced sweep
        bf16* Y3 = (bf16*)smem;                      // [128][264]
        #pragma unroll
        for (int h = 0; h < 2; h++) {
            if ((wc >> 1) == h) {
                #pragma unroll
                for (int j = 0; j < 4; j++) {
                    const int nl = (wc & 1) * 64 + j * 16 + l16;
                    const float bv = bias[n0 + wc * 64 + j * 16 + l16];
                    #pragma unroll
                    for (int i = 0; i < 8; i++) {
                        bf16 tmp[4];
                        #pragma unroll
                        for (int r = 0; r < 4; r++) tmp[r] = (bf16)(acc[i][j][r] + bv);
                        *(ushort4*)&Y3[nl * 264 + wr * 128 + i * 16 + quad * 4] =
                            *(const ushort4*)tmp;
                    }
                }
            }
            __syncthreads();
            const int nl = tid >> 5, m8 = (tid & 31) * 8;
            #pragma unroll
            for (int kk = 0; kk < 8; kk++)
                *(uint4*)&out[(size_t)(n0 + h * 128 + nl + kk * 16) * kNTOK + m0 + m8] =
                    *(const uint4*)&Y3[(nl + kk * 16) * 264 + m8];
            __syncthreads();
        }
    } else {
        // RoPE epilogue, one head (128 cols) per phase. Y: [256][136] bf16.
        bf16* Y = (bf16*)smem;
        #pragma unroll
        for (int h = 0; h < 2; h++) {
            if ((wc >> 1) == h && (wc & 1)) {        // deposit x2 (d in [64,128))
                #pragma unroll
                for (int j = 0; j < 4; j++) {
                    const int dj = j * 16 + l16;
                    const float bv = bias[n0 + wc * 64 + j * 16 + l16];
                    #pragma unroll
                    for (int i = 0; i < 8; i++)
                        #pragma unroll
                        for (int r = 0; r < 4; r++)
                            Y[(wr * 128 + i * 16 + quad * 4 + r) * 136 + 64 + dj] =
                                (bf16)(acc[i][j][r] + bv);
                }
            }
            __syncthreads();
            if ((wc >> 1) == h && !(wc & 1)) {       // rotate (d in [0,64))
                #pragma unroll
                for (int j = 0; j < 4; j++) {
                    const int d = j * 16 + l16;
                    const float bv = bias[n0 + wc * 64 + j * 16 + l16];
                    const float invf = exp2f((float)d * -0.20762050593045951f); // log2(1e4)/64
                    #pragma unroll
                    for (int i = 0; i < 8; i++) {
                        #pragma unroll
                        for (int r = 0; r < 4; r++) {
                            const int mloc = wr * 128 + i * 16 + quad * 4 + r;
                            const int tok = m0 + mloc;
                            int pt, ph, pw;
                            if (MODE == 2) { pt = tok >> 10; ph = (tok >> 5) & 31; pw = tok & 31; }
                            else { int tq = tok >> 8; pt = (31 * tq) / 7;
                                   ph = 2 * ((tok >> 4) & 15) + 1; pw = 2 * (tok & 15) + 1; }
                            const int p = (d < 16) ? pt : ((d < 40) ? ph : pw);
                            float sn, cs;
                            __sincosf((float)p * invf, &sn, &cs);
                            const float x1 = acc[i][j][r] + bv;
                            const float x2 = (float)Y[mloc * 136 + 64 + d];
                            Y[mloc * 136 + d]      = (bf16)(x1 * cs - x2 * sn);
                            Y[mloc * 136 + 64 + d] = (bf16)(x2 * cs + x1 * sn);
                        }
                    }
                }
            }
            __syncthreads();
            const int rrow = tid >> 1, seg = (tid & 1) * 64;
            #pragma unroll
            for (int kk = 0; kk < 8; kk++)
                *(uint4*)&out[(size_t)(m0 + rrow) * kDM + n0 + h * 128 + seg + kk * 8] =
                    *(const uint4*)&Y[rrow * 136 + seg + kk * 8];
            __syncthreads();
        }
    }
}

// ---------------------------------------------------------------------------
// Flash attention, 4-way key split. Grid (z=32, h=8, qb=4) = 1024 blocks =
// exactly 4/CU at 40KB LDS (perfect fill, no tail). l (row-sum of P) via
// MFMA with an all-ones B-fragment built in registers (lane-uniform -> no
// LDS). Ps XOR-swizzled to 8KB unpadded.
// ---------------------------------------------------------------------------
__global__ __launch_bounds__(256) void attn_kernel(
    const bf16* __restrict__ qh, const bf16* __restrict__ kh,
    const bf16* __restrict__ vt, float* __restrict__ Opart, float* __restrict__ ml)
{
    __shared__ bf16 Ks[64 * 128];    // [key][d], 16B-granule swizzle by key&15
    __shared__ bf16 Vs[128 * 64];    // [d][key], 16B-granule swizzle by d&7
    __shared__ bf16 Ps[4][16][64];   // per-wave P, col ^ ((row&7)*8) swizzle

    const int tid  = threadIdx.x;
    const int z    = blockIdx.x, h = blockIdx.y, qb = blockIdx.z;
    const int t    = z >> 2, sp = z & 3;
    const int wave = tid >> 6;
    const int lane = tid & 63;
    const int quad = lane >> 4, l16 = lane & 15;

    const int qrow = qb * 64 + wave * 16 + l16;
    const size_t qbase = ((size_t)(t * 256 + qrow)) * kDM + h * 128;
    bf16x8 aq[4];
    #pragma unroll
    for (int kb = 0; kb < 4; kb++)
        aq[kb] = *(const bf16x8*)&qh[qbase + kb * 32 + quad * 8];

    bf16x8 ones;
    #pragma unroll
    for (int e = 0; e < 8; e++) ones[e] = (bf16)1.0f;

    f32x4 o[9];
    #pragma unroll
    for (int j = 0; j < 9; j++) o[j] = zero4();
    float m_run[4];
    #pragma unroll
    for (int r = 0; r < 4; r++) m_run[r] = -1e30f;
    const float scale = 0.08838834764831845f;   // 1/sqrt(128)

    const int r16 = lane >> 4, j16 = lane & 15;  // K staging coords
    const int r8  = lane >> 3, j8  = lane & 7;   // V staging coords

    for (int kt = 0; kt < 16; kt++) {
        const int kbase = t * 4096 + sp * 1024 + kt * 64;
        __syncthreads();
        #pragma unroll
        for (int i = 0; i < 4; i++) {   // K: 16 chunks (4 key rows each)
            const int c = wave * 4 + i;
            const int krow = c * 4 + r16;
            GLOAD_LDS16(&kh[(size_t)(kbase + krow) * kDM + h * 128 + ((j16 ^ (krow & 15)) * 8)],
                        &Ks[c * 512]);
        }
        #pragma unroll
        for (int i = 0; i < 4; i++) {   // V^T: 16 chunks (8 d rows x 64 keys)
            const int c = wave * 4 + i;
            GLOAD_LDS16(&vt[(size_t)(h * 128 + c * 8 + r8) * kNTOK + kbase + ((j8 ^ r8) * 8)],
                        &Vs[c * 512]);
        }
        __syncthreads();

        // S = Q K^T : 16 q x 64 keys per wave
        f32x4 s[4];
        #pragma unroll
        for (int c = 0; c < 4; c++) s[c] = zero4();
        #pragma unroll
        for (int kb = 0; kb < 4; kb++) {
            #pragma unroll
            for (int c = 0; c < 4; c++) {
                bf16x8 b = *(const bf16x8*)&Ks[(c * 16 + l16) * 128 + (((kb * 4 + quad) ^ l16) * 8)];
                s[c] = MFMA16(aq[kb], b, s[c]);
            }
        }

        // online softmax (max via shfl; sum via ones-frag MFMA)
        float alpha[4];
        #pragma unroll
        for (int r = 0; r < 4; r++) {
            float sv[4];
            #pragma unroll
            for (int c = 0; c < 4; c++) sv[c] = s[c][r] * scale;
            float mx = fmaxf(fmaxf(sv[0], sv[1]), fmaxf(sv[2], sv[3]));
            #pragma unroll
            for (int off = 1; off < 16; off <<= 1) mx = fmaxf(mx, __shfl_xor(mx, off));
            const float mn = fmaxf(m_run[r], mx);
            alpha[r] = __expf(m_run[r] - mn);
            m_run[r] = mn;
            const int q7 = quad * 4 + r;
            #pragma unroll
            for (int c = 0; c < 4; c++) {
                const int col = (c * 16 + l16) ^ ((q7 & 7) * 8);
                Ps[wave][q7][col] = (bf16)__expf(sv[c] - mn);
            }
        }
        #pragma unroll
        for (int j = 0; j < 9; j++)
            #pragma unroll
            for (int r = 0; r < 4; r++) o[j][r] *= alpha[r];
        #pragma unroll
        for (int ks = 0; ks < 2; ks++) {
            bf16x8 pa = *(const bf16x8*)&Ps[wave][l16][((ks * 4 + quad) ^ (l16 & 7)) * 8];
            #pragma unroll
            for (int j = 0; j < 8; j++) {
                bf16x8 bv = *(const bf16x8*)&Vs[(j * 16 + l16) * 64 + (((ks * 4 + quad) ^ (l16 & 7)) * 8)];
                o[j] = MFMA16(pa, bv, o[j]);
            }
            o[8] = MFMA16(pa, ones, o[8]);
        }
    }

    #pragma unroll
    for (int r = 0; r < 4; r++) {
        const int srow = qb * 64 + wave * 16 + quad * 4 + r;
        const size_t pr = ((size_t)(z * 8 + h)) * 256 + srow;
        #pragma unroll
        for (int j = 0; j < 8; j++)
            Opart[pr * 128 + j * 16 + l16] = o[j][r];
        if (l16 == 0) { ml[pr * 2] = m_run[r]; ml[pr * 2 + 1] = o[8][r]; }
    }
}

// ---------------------------------------------------------------------------
// Combine 4 splits: O = sum O_sp*exp(m_sp-m*) / sum l_sp*exp(m_sp-m*)
// ---------------------------------------------------------------------------
__global__ __launch_bounds__(256) void combine_kernel(
    const float* __restrict__ Opart, const float* __restrict__ ml,
    float* __restrict__ out)
{
    const int tid = threadIdx.x;
    const int rid = blockIdx.x * 2 + (tid >> 7);
    const int d   = tid & 127;
    const int t = rid >> 11, h = (rid >> 8) & 7, srow = rid & 255;

    float mv[4], lv[4];
    #pragma unroll
    for (int sp = 0; sp < 4; sp++) {
        const size_t pr = ((size_t)((t * 4 + sp) * 8 + h)) * 256 + srow;
        float2 p = *(const float2*)&ml[pr * 2];
        mv[sp] = p.x; lv[sp] = p.y;
    }
    const float ms = fmaxf(fmaxf(mv[0], mv[1]), fmaxf(mv[2], mv[3]));
    float lsum = 0.f, acc = 0.f;
    #pragma unroll
    for (int sp = 0; sp < 4; sp++) {
        const size_t pr = ((size_t)((t * 4 + sp) * 8 + h)) * 256 + srow;
        const float w = __expf(mv[sp] - ms);
        lsum += lv[sp] * w;
        acc  += Opart[pr * 128 + d] * w;
    }
    out[((size_t)(t * 256 + srow)) * kDM + h * 128 + d] = acc / lsum;
}

// ---------------------------------------------------------------------------
extern "C" void kernel_launch(void* const* d_in, const int* in_sizes, int n_in,
                              void* d_out, int out_size, void* d_ws, size_t ws_size,
                              hipStream_t stream)
{
    const float* q  = (const float*)d_in[0];
    const float* k  = (const float*)d_in[1];
    const float* v  = (const float*)d_in[2];
    const float* Wq = (const float*)d_in[3];
    const float* bq = (const float*)d_in[4];
    const float* Wk = (const float*)d_in[5];
    const float* bk = (const float*)d_in[6];
    const float* Wv = (const float*)d_in[7];
    const float* bv = (const float*)d_in[8];
    float* out = (float*)d_out;

    // ws: qh 4MB | kh 64MB | vt 64MB | Wt x3 6MB | Opart 33.5MB | ml 0.5MB
    bf16* qh  = (bf16*)d_ws;
    bf16* kh  = qh + (size_t)2048 * 1024;
    bf16* vt  = kh + (size_t)32768 * 1024;
    bf16* Wqt = vt + (size_t)32768 * 1024;
    bf16* Wkt = Wqt + (size_t)1024 * 1024;
    bf16* Wvt = Wkt + (size_t)1024 * 1024;
    float* Opart = (float*)(Wvt + (size_t)1024 * 1024);
    float* ml    = Opart + (size_t)32 * 8 * 256 * 128;

    transpose_all<<<dim3(16, 16, 3), 256, 0, stream>>>(Wq, Wk, Wv, Wqt, Wkt, Wvt);
    gemm_fused<1><<<32,  512, 0, stream>>>(q, Wqt, bq, qh, 1);     // q proj + slow rope
    gemm_fused<2><<<512, 512, 0, stream>>>(k, Wkt, bk, kh, 16);    // k proj + fast rope
    gemm_fused<3><<<512, 512, 0, stream>>>(v, Wvt, bv, vt, 16);    // v proj, transposed
    attn_kernel<<<dim3(32, 8, 4), 256, 0, stream>>>(qh, kh, vt, Opart, ml);
    combine_kernel<<<8192, 256, 0, stream>>>(Opart, ml, out);
}